// Round 10
// baseline (1847.697 us; speedup 1.0000x reference)
//
#include <hip/hip_runtime.h>
#include <stdint.h>
#include <stddef.h>

#define M_SZ 8192
#define F_DIM 512
#define N_Q 32768

typedef __attribute__((ext_vector_type(4))) float f32x4;
typedef __attribute__((ext_vector_type(8))) __bf16 bf16x8;
typedef __attribute__((ext_vector_type(2))) __bf16 bf16x2;

__device__ __forceinline__ float bits_to_f(unsigned u) {
    union { unsigned u; float f; } v; v.u = u; return v.f;
}
// Pack two floats to bf16 pair (RNE, native cvt). Low 16 = a.
__device__ __forceinline__ unsigned pk_bf16(float a, float b) {
    union { bf16x2 v; unsigned u; } cv;
    cv.v.x = (__bf16)a; cv.v.y = (__bf16)b;
    return cv.u;
}
__device__ __forceinline__ unsigned short f2bf(float x) {
    union { bf16x2 v; unsigned u; } cv;
    cv.v.x = (__bf16)x; cv.v.y = (__bf16)0.0f;
    return (unsigned short)(cv.u & 0xffffu);
}
__device__ __forceinline__ bf16x8 as_bf16x8(uint4 u) {
    union { uint4 a; bf16x8 b; } cv; cv.a = u; return cv.b;
}
__device__ __forceinline__ bf16x8 mk_bf16x8(unsigned a, unsigned b, unsigned c, unsigned d) {
    union { uint4 a; bf16x8 b; } cv; cv.a = make_uint4(a, b, c, d); return cv.b;
}

// ---------------------------------------------------------------------------
// Kernel 1: row-normalize positions & embeddings; pad to float4.
// ---------------------------------------------------------------------------
__global__ void prep_kernel(const float* __restrict__ pos,
                            const float* __restrict__ emb,
                            float* __restrict__ pn4,
                            float* __restrict__ en4,
                            float* __restrict__ pos4) {
    int i = blockIdx.x * 256 + threadIdx.x;
    if (i >= M_SZ) return;
    float x = pos[i * 3 + 0], y = pos[i * 3 + 1], z = pos[i * 3 + 2];
    float inv = 1.0f / __builtin_amdgcn_sqrtf(x * x + y * y + z * z);
    pn4[i * 4 + 0] = x * inv; pn4[i * 4 + 1] = y * inv;
    pn4[i * 4 + 2] = z * inv; pn4[i * 4 + 3] = 0.0f;
    pos4[i * 4 + 0] = x; pos4[i * 4 + 1] = y;
    pos4[i * 4 + 2] = z; pos4[i * 4 + 3] = 0.0f;
    float ex = emb[i * 3 + 0], ey = emb[i * 3 + 1], ez = emb[i * 3 + 2];
    float einv = 1.0f / __builtin_amdgcn_sqrtf(ex * ex + ey * ey + ez * ez);
    en4[i * 4 + 0] = ex * einv; en4[i * 4 + 1] = ey * einv;
    en4[i * 4 + 2] = ez * einv; en4[i * 4 + 3] = 0.0f;
}

// ---------------------------------------------------------------------------
// Kernel 2: features [8192,512] fp32 -> featT [512,8192] bf16.
// ---------------------------------------------------------------------------
__global__ void transpose_kernel(const float* __restrict__ feat,
                                 unsigned short* __restrict__ featT) {
    __shared__ float tile[64 * 65];
    const int jb = blockIdx.x * 64, fb = blockIdx.y * 64;
    const int t = threadIdx.x;
#pragma unroll
    for (int p = 0; p < 16; ++p) {
        int idx = p * 256 + t;
        int j = idx >> 6, f = idx & 63;
        tile[j * 65 + f] = feat[(size_t)(jb + j) * F_DIM + fb + f];
    }
    __syncthreads();
#pragma unroll
    for (int p = 0; p < 16; ++p) {
        int idx = p * 256 + t;
        int f = idx >> 6, j = idx & 63;
        featT[(size_t)(fb + f) * M_SZ + jb + j] = f2bf(tile[j * 65 + f]);
    }
}

// ---------------------------------------------------------------------------
// Kernel 3 (v5): softmax(pn@en^T) @ [features | positions] with REGISTER-A:
// each lane computes exactly the A-fragment weights its MFMA lanes need
// (row = mf*16 + lane&15, k = quad*8+i). NO LDS staging, NO K-loop barriers
// -> 8 independent waves/CU, MFMA/VALU/VMEM overlap via TLP.
// BM=64 (2 wm-waves x 2 frags), BN=256 (4 wn-waves x 4 frags), fb=bid&1.
// Grid 256 = 128 m-tiles x 2 f-halves; XCD sees one 4MB featT slice (L2-fit).
// npe accumulated only by fb==0,wn==0 waves (row-unique).
// ---------------------------------------------------------------------------
__launch_bounds__(512, 2)
__global__ void build_memory_kernel(const float* __restrict__ pn4,
                                    const float* __restrict__ en4,
                                    const float* __restrict__ pos4,
                                    const unsigned short* __restrict__ featT,
                                    unsigned short* __restrict__ memT,
                                    float* __restrict__ npe4) {
    __shared__ float lbuf[64];

    const int t = threadIdx.x;
    const int wvid = t >> 6, l = t & 63;
    const int wm = wvid >> 2, wn = wvid & 3;
    const int col = l & 15, quad = l >> 4;
    const int bid = blockIdx.x;
    const int fb = bid & 1;
    const int mb = (bid >> 1) * 64;

    const f32x4* en = (const f32x4*)en4;
    const f32x4* ps = (const f32x4*)pos4;

    // per-lane row constants (2 m-frags)
    f32x4 pnc[2];
#pragma unroll
    for (int mf = 0; mf < 2; ++mf)
        pnc[mf] = ((const f32x4*)pn4)[mb + (wm * 2 + mf) * 16 + col];

    const bool donpe = (fb == 0) && (wn == 0);

    // B base: f-row = fb*256 + (wn*4+nf)*16 + col, k-offset quad*8
    const unsigned short* bB =
        featT + (size_t)(fb * 256 + wn * 64 + col) * M_SZ + quad * 8;

    f32x4 acc[2][4];
    const f32x4 zero4 = {0.f, 0.f, 0.f, 0.f};
#pragma unroll
    for (int mf = 0; mf < 2; ++mf)
#pragma unroll
        for (int nf = 0; nf < 4; ++nf) acc[mf][nf] = zero4;
    float lp2[2] = {0.f, 0.f};
    float nxa[2] = {0.f, 0.f}, nya[2] = {0.f, 0.f}, nza[2] = {0.f, 0.f};

    for (int kt = 0; kt < 256; ++kt) {
        const int k0 = kt * 32 + quad * 8;
        // B loads (4 x uint4) — covered by the A-gen VALU below + wave TLP
        uint4 vb[4];
#pragma unroll
        for (int nf = 0; nf < 4; ++nf)
            vb[nf] = *(const uint4*)(bB + (size_t)nf * 16 * M_SZ + kt * 32);
        // en / ps slices (broadcast within quad-groups, tiny working set)
        f32x4 ee[8];
#pragma unroll
        for (int i = 0; i < 8; ++i) ee[i] = en[k0 + i];

        bf16x8 af[2];
#pragma unroll
        for (int mf = 0; mf < 2; ++mf) {
            unsigned au[4];
#pragma unroll
            for (int i = 0; i < 8; i += 2) {
                float s0 = fmaf(pnc[mf].x, ee[i].x,
                           fmaf(pnc[mf].y, ee[i].y, pnc[mf].z * ee[i].z));
                float s1 = fmaf(pnc[mf].x, ee[i + 1].x,
                           fmaf(pnc[mf].y, ee[i + 1].y, pnc[mf].z * ee[i + 1].z));
                float w0 = __builtin_amdgcn_exp2f(s0 * 1.44269504f);
                float w1 = __builtin_amdgcn_exp2f(s1 * 1.44269504f);
                unsigned u = pk_bf16(w0, w1);
                au[i >> 1] = u;
                float w0r = bits_to_f(u << 16), w1r = bits_to_f(u & 0xffff0000u);
                lp2[mf] += w0r + w1r;
                if (donpe) {
                    f32x4 p0 = ps[k0 + i], p1 = ps[k0 + i + 1];
                    nxa[mf] = fmaf(w0r, p0.x, fmaf(w1r, p1.x, nxa[mf]));
                    nya[mf] = fmaf(w0r, p0.y, fmaf(w1r, p1.y, nya[mf]));
                    nza[mf] = fmaf(w0r, p0.z, fmaf(w1r, p1.z, nza[mf]));
                }
            }
            af[mf] = mk_bf16x8(au[0], au[1], au[2], au[3]);
        }
#pragma unroll
        for (int nf = 0; nf < 4; ++nf) {
            acc[0][nf] = __builtin_amdgcn_mfma_f32_16x16x32_bf16(
                af[0], as_bf16x8(vb[nf]), acc[0][nf], 0, 0, 0);
            acc[1][nf] = __builtin_amdgcn_mfma_f32_16x16x32_bf16(
                af[1], as_bf16x8(vb[nf]), acc[1][nf], 0, 0, 0);
        }
    }

    // row-sum reduction across quads (lanes l, l^16, l^32, l^48 share a row)
    float lsum[2];
#pragma unroll
    for (int mf = 0; mf < 2; ++mf) {
        float s = lp2[mf];
        s += __shfl_xor(s, 16);
        s += __shfl_xor(s, 32);
        lsum[mf] = s;
        if (quad == 0 && wn == 0) lbuf[(wm * 2 + mf) * 16 + col] = s;
    }
    if (donpe) {
#pragma unroll
        for (int mf = 0; mf < 2; ++mf) {
            float sx = nxa[mf]; sx += __shfl_xor(sx, 16); sx += __shfl_xor(sx, 32);
            float sy = nya[mf]; sy += __shfl_xor(sy, 16); sy += __shfl_xor(sy, 32);
            float sz = nza[mf]; sz += __shfl_xor(sz, 16); sz += __shfl_xor(sz, 32);
            if (quad == 0) {
                float inv = 1.0f / lsum[mf];
                float X = sx * inv, Y = sy * inv, Z = sz * inv;
                f32x4 o = {X, Y, Z, X * X + Y * Y + Z * Z};
                ((f32x4*)npe4)[mb + (wm * 2 + mf) * 16 + col] = o;
            }
        }
    }
    __syncthreads();

    // memT[f][m] = acc / l   (D: row = quad*4+reg (m), col = lane&15 (f))
#pragma unroll
    for (int mf = 0; mf < 2; ++mf) {
        f32x4 l4 = *(const f32x4*)(lbuf + (wm * 2 + mf) * 16 + quad * 4);
        f32x4 inv4 = {1.0f / l4.x, 1.0f / l4.y, 1.0f / l4.z, 1.0f / l4.w};
        int mg = mb + (wm * 2 + mf) * 16 + quad * 4;
#pragma unroll
        for (int nf = 0; nf < 4; ++nf) {
            int fg = fb * 256 + (wn * 4 + nf) * 16 + col;
            uint2 o;
            o.x = pk_bf16(acc[mf][nf].x * inv4.x, acc[mf][nf].y * inv4.y);
            o.y = pk_bf16(acc[mf][nf].z * inv4.z, acc[mf][nf].w * inv4.w);
            *(uint2*)(memT + (size_t)fg * M_SZ + mg) = o;
        }
    }
}

// ---------------------------------------------------------------------------
// Kernel 4 (v5): softmax(-cdist(q,npe)) @ memory with REGISTER-A, no LDS
// staging, no K-loop barriers. BM=256 (8 waves x 2 m-frags), BN=256
// (16 n-frags per wave), fb=bid&1. Grid 256 = 128 q-tiles x 2 f-halves
// -> memT traffic halved to 1 GB and each XCD's 4MB slice is L2-resident.
// acc = 128 AGPR; B loaded in two batches of 8 to cap VGPR below 256.
// ---------------------------------------------------------------------------
__launch_bounds__(512, 2)
__global__ void query_kernel(const float* __restrict__ qpos,
                             const float* __restrict__ npe4,
                             const unsigned short* __restrict__ memT,
                             float* __restrict__ out) {
    __shared__ float lbuf[256];

    const int t = threadIdx.x;
    const int wv = t >> 6, l = t & 63;
    const int col = l & 15, quad = l >> 4;
    const int bid = blockIdx.x;
    const int fb = bid & 1;
    const int qb = (bid >> 1) * 256;

    // per-lane q-row constants for the wave's 2 m-frags
    float m2x[2], m2y[2], m2z[2], q2c[2];
#pragma unroll
    for (int mf = 0; mf < 2; ++mf) {
        int r = qb + (wv * 2 + mf) * 16 + col;
        float qx = qpos[(size_t)r * 3 + 0];
        float qy = qpos[(size_t)r * 3 + 1];
        float qz = qpos[(size_t)r * 3 + 2];
        q2c[mf] = qx * qx + qy * qy + qz * qz;
        m2x[mf] = -2.0f * qx; m2y[mf] = -2.0f * qy; m2z[mf] = -2.0f * qz;
    }

    const f32x4* nsrc = (const f32x4*)npe4;
    const unsigned short* bB =
        memT + (size_t)(fb * 256 + col) * M_SZ + quad * 8;

    f32x4 acc[2][16];
    const f32x4 zero4 = {0.f, 0.f, 0.f, 0.f};
#pragma unroll
    for (int mf = 0; mf < 2; ++mf)
#pragma unroll
        for (int nf = 0; nf < 16; ++nf) acc[mf][nf] = zero4;
    float lp2[2] = {0.f, 0.f};

    for (int kt = 0; kt < 256; ++kt) {
        const int k0 = kt * 32 + quad * 8;
        uint4 vb[8];
        // batch 0 loads — covered by npe loads + A-gen VALU
#pragma unroll
        for (int nf = 0; nf < 8; ++nf)
            vb[nf] = *(const uint4*)(bB + (size_t)nf * 16 * M_SZ + kt * 32);
        f32x4 nn[8];
#pragma unroll
        for (int i = 0; i < 8; ++i) nn[i] = nsrc[k0 + i];

        bf16x8 af[2];
#pragma unroll
        for (int mf = 0; mf < 2; ++mf) {
            unsigned au[4];
#pragma unroll
            for (int i = 0; i < 8; i += 2) {
                float s0 = fmaf(m2x[mf], nn[i].x, fmaf(m2y[mf], nn[i].y,
                           fmaf(m2z[mf], nn[i].z, q2c[mf] + nn[i].w)));
                float s1 = fmaf(m2x[mf], nn[i + 1].x, fmaf(m2y[mf], nn[i + 1].y,
                           fmaf(m2z[mf], nn[i + 1].z, q2c[mf] + nn[i + 1].w)));
                s0 = fmaxf(s0, 1e-12f); s1 = fmaxf(s1, 1e-12f);
                float w0 = __builtin_amdgcn_exp2f(
                    __builtin_amdgcn_sqrtf(s0) * -1.44269504f);
                float w1 = __builtin_amdgcn_exp2f(
                    __builtin_amdgcn_sqrtf(s1) * -1.44269504f);
                unsigned u = pk_bf16(w0, w1);
                au[i >> 1] = u;
                lp2[mf] += bits_to_f(u << 16) + bits_to_f(u & 0xffff0000u);
            }
            af[mf] = mk_bf16x8(au[0], au[1], au[2], au[3]);
        }
#pragma unroll
        for (int nf = 0; nf < 8; ++nf) {
            acc[0][nf] = __builtin_amdgcn_mfma_f32_16x16x32_bf16(
                af[0], as_bf16x8(vb[nf]), acc[0][nf], 0, 0, 0);
            acc[1][nf] = __builtin_amdgcn_mfma_f32_16x16x32_bf16(
                af[1], as_bf16x8(vb[nf]), acc[1][nf], 0, 0, 0);
        }
        // batch 1 loads — issued while batch-0 MFMAs drain; covered by them
        // + sibling-wave TLP
#pragma unroll
        for (int nf = 0; nf < 8; ++nf)
            vb[nf] = *(const uint4*)(bB + (size_t)(8 + nf) * 16 * M_SZ + kt * 32);
#pragma unroll
        for (int nf = 0; nf < 8; ++nf) {
            acc[0][8 + nf] = __builtin_amdgcn_mfma_f32_16x16x32_bf16(
                af[0], as_bf16x8(vb[nf]), acc[0][8 + nf], 0, 0, 0);
            acc[1][8 + nf] = __builtin_amdgcn_mfma_f32_16x16x32_bf16(
                af[1], as_bf16x8(vb[nf]), acc[1][8 + nf], 0, 0, 0);
        }
    }

    // row-sum reduction across quads, redistribute via tiny LDS
#pragma unroll
    for (int mf = 0; mf < 2; ++mf) {
        float s = lp2[mf];
        s += __shfl_xor(s, 16);
        s += __shfl_xor(s, 32);
        if (quad == 0) lbuf[(wv * 2 + mf) * 16 + col] = s;
    }
    __syncthreads();

#pragma unroll
    for (int mf = 0; mf < 2; ++mf) {
        f32x4 l4 = *(const f32x4*)(lbuf + (wv * 2 + mf) * 16 + quad * 4);
        f32x4 inv4 = {1.0f / l4.x, 1.0f / l4.y, 1.0f / l4.z, 1.0f / l4.w};
        int qg = qb + (wv * 2 + mf) * 16 + quad * 4;
#pragma unroll
        for (int nf = 0; nf < 16; ++nf) {
            int fg = fb * 256 + nf * 16 + col;
            out[(size_t)(qg + 0) * F_DIM + fg] = acc[mf][nf].x * inv4.x;
            out[(size_t)(qg + 1) * F_DIM + fg] = acc[mf][nf].y * inv4.y;
            out[(size_t)(qg + 2) * F_DIM + fg] = acc[mf][nf].z * inv4.z;
            out[(size_t)(qg + 3) * F_DIM + fg] = acc[mf][nf].w * inv4.w;
        }
    }
}

// ---------------------------------------------------------------------------
// Workspace layout (bytes):
//   featT : [0,        8388608)   512x8192 bf16
//   memT  : [8388608, 16777216)   512x8192 bf16
//   npe4  : [16777216,16908288)   8192x4 fp32 (x,y,z,|npe|^2)
//   pn4   : [16908288,17039360)
//   en4   : [17039360,17170432)
//   pos4  : [17170432,17301504)
// ---------------------------------------------------------------------------
extern "C" void kernel_launch(void* const* d_in, const int* in_sizes, int n_in,
                              void* d_out, int out_size, void* d_ws, size_t ws_size,
                              hipStream_t stream) {
    const float* features  = (const float*)d_in[0];
    const float* positions = (const float*)d_in[1];
    const float* qpos      = (const float*)d_in[2];
    const float* pemb      = (const float*)d_in[3];
    float* out = (float*)d_out;
    char* ws = (char*)d_ws;

    unsigned short* featT = (unsigned short*)(ws);
    unsigned short* memT  = (unsigned short*)(ws + 8388608);
    float* npe4 = (float*)(ws + 16777216);
    float* pn4  = (float*)(ws + 16908288);
    float* en4  = (float*)(ws + 17039360);
    float* pos4 = (float*)(ws + 17170432);

    hipLaunchKernelGGL(prep_kernel, dim3(M_SZ / 256), dim3(256), 0, stream,
                       positions, pemb, pn4, en4, pos4);
    hipLaunchKernelGGL(transpose_kernel, dim3(M_SZ / 64, F_DIM / 64), dim3(256), 0, stream,
                       features, featT);
    hipLaunchKernelGGL(build_memory_kernel, dim3((M_SZ / 64) * 2), dim3(512), 0, stream,
                       pn4, en4, pos4, featT, memT, npe4);
    hipLaunchKernelGGL(query_kernel, dim3((N_Q / 256) * 2), dim3(512), 0, stream,
                       qpos, npe4, memT, out);
}

// Round 11
// 933.624 us; speedup vs baseline: 1.9791x; 1.9791x over previous
//
#include <hip/hip_runtime.h>
#include <stdint.h>
#include <stddef.h>

#define M_SZ 8192
#define F_DIM 512
#define N_Q 32768

typedef __attribute__((ext_vector_type(4))) float f32x4;
typedef __attribute__((ext_vector_type(8))) __bf16 bf16x8;
typedef __attribute__((ext_vector_type(2))) __bf16 bf16x2;

__device__ __forceinline__ float bits_to_f(unsigned u) {
    union { unsigned u; float f; } v; v.u = u; return v.f;
}
__device__ __forceinline__ unsigned pk_bf16(float a, float b) {
    union { bf16x2 v; unsigned u; } cv;
    cv.v.x = (__bf16)a; cv.v.y = (__bf16)b;
    return cv.u;
}
__device__ __forceinline__ unsigned short f2bf(float x) {
    union { bf16x2 v; unsigned u; } cv;
    cv.v.x = (__bf16)x; cv.v.y = (__bf16)0.0f;
    return (unsigned short)(cv.u & 0xffffu);
}
__device__ __forceinline__ bf16x8 as_bf16x8(uint4 u) {
    union { uint4 a; bf16x8 b; } cv; cv.a = u; return cv.b;
}
__device__ __forceinline__ bf16x8 mk_bf16x8(unsigned a, unsigned b, unsigned c, unsigned d) {
    union { uint4 a; bf16x8 b; } cv; cv.a = make_uint4(a, b, c, d); return cv.b;
}

// ---------------------------------------------------------------------------
// Kernel 1: row-normalize positions & embeddings; pad to float4.
// ---------------------------------------------------------------------------
__global__ void prep_kernel(const float* __restrict__ pos,
                            const float* __restrict__ emb,
                            float* __restrict__ pn4,
                            float* __restrict__ en4,
                            float* __restrict__ pos4) {
    int i = blockIdx.x * 256 + threadIdx.x;
    if (i >= M_SZ) return;
    float x = pos[i * 3 + 0], y = pos[i * 3 + 1], z = pos[i * 3 + 2];
    float inv = 1.0f / __builtin_amdgcn_sqrtf(x * x + y * y + z * z);
    pn4[i * 4 + 0] = x * inv; pn4[i * 4 + 1] = y * inv;
    pn4[i * 4 + 2] = z * inv; pn4[i * 4 + 3] = 0.0f;
    pos4[i * 4 + 0] = x; pos4[i * 4 + 1] = y;
    pos4[i * 4 + 2] = z; pos4[i * 4 + 3] = 0.0f;
    float ex = emb[i * 3 + 0], ey = emb[i * 3 + 1], ez = emb[i * 3 + 2];
    float einv = 1.0f / __builtin_amdgcn_sqrtf(ex * ex + ey * ey + ez * ez);
    en4[i * 4 + 0] = ex * einv; en4[i * 4 + 1] = ey * einv;
    en4[i * 4 + 2] = ez * einv; en4[i * 4 + 3] = 0.0f;
}

// ---------------------------------------------------------------------------
// Kernel 2: features [8192,512] fp32 -> featT [512,8192] bf16.
// ---------------------------------------------------------------------------
__global__ void transpose_kernel(const float* __restrict__ feat,
                                 unsigned short* __restrict__ featT) {
    __shared__ float tile[64 * 65];
    const int jb = blockIdx.x * 64, fb = blockIdx.y * 64;
    const int t = threadIdx.x;
#pragma unroll
    for (int p = 0; p < 16; ++p) {
        int idx = p * 256 + t;
        int j = idx >> 6, f = idx & 63;
        tile[j * 65 + f] = feat[(size_t)(jb + j) * F_DIM + fb + f];
    }
    __syncthreads();
#pragma unroll
    for (int p = 0; p < 16; ++p) {
        int idx = p * 256 + t;
        int f = idx >> 6, j = idx & 63;
        featT[(size_t)(fb + f) * M_SZ + jb + j] = f2bf(tile[j * 65 + f]);
    }
}

// ---------------------------------------------------------------------------
// Kernel 3 (v6): register-A (computed per lane, v5-verified layout) +
// LDS-shared B in fragment order. BM=128 (8 waves x 16 rows), BN=128
// (8 nf frags), BK=32. fb=bid&3 -> each XCD reuses one 2MB featT slice.
// featT traffic = unique = 537 MB total (was ~2.1 GB in v5).
// LDS layout: chunk c (= nf*64 + lane, lane = quad*16+col) at byte c*16 ->
// every ds_read_b128/ds_write_b128 is base + lane*16 (conflict-free).
// One barrier per K-iter; staging loads issued at iter top, written at end.
// ---------------------------------------------------------------------------
__launch_bounds__(512, 2)
__global__ void build_memory_kernel(const float* __restrict__ pn4,
                                    const float* __restrict__ en4,
                                    const float* __restrict__ pos4,
                                    const unsigned short* __restrict__ featT,
                                    unsigned short* __restrict__ memT,
                                    float* __restrict__ npe4) {
    constexpr int NF = 8;                     // BN = 128
    __shared__ unsigned short pbuf[2][NF * 512];  // 8 KiB per side
    __shared__ float lbuf[128];

    const int t = threadIdx.x;
    const int wv = t >> 6, l = t & 63;
    const int col = l & 15, quad = l >> 4;
    const int bid = blockIdx.x;
    const int fb = bid & 3;                   // f-quarter: XCD-affine
    const int mb = (bid >> 2) * 128;

    const f32x4* en = (const f32x4*)en4;
    const f32x4* ps = (const f32x4*)pos4;

    // per-lane A-row constants: row = mb + wv*16 + col
    const f32x4 pnc = ((const f32x4*)pn4)[mb + wv * 16 + col];
    const bool donpe = (fb == 0);

    // staging: thread t owns chunk c = t; row = fb*128 + (c>>6)*16 + (c&15),
    // k-chunk = (c>>4)&3. dst = pbuf[side] + c*8 shorts (byte c*16).
    const unsigned short* sp =
        featT + (size_t)(fb * 128 + (t >> 6) * 16 + (t & 15)) * M_SZ + ((t >> 4) & 3) * 8;

    f32x4 acc[NF];
    const f32x4 zero4 = {0.f, 0.f, 0.f, 0.f};
#pragma unroll
    for (int nf = 0; nf < NF; ++nf) acc[nf] = zero4;
    float lp = 0.f, nxa = 0.f, nya = 0.f, nza = 0.f;

    // prologue: stage kt = 0 into side 0
    {
        uint4 s0 = *(const uint4*)(sp);
        *(uint4*)(&pbuf[0][t * 8]) = s0;
    }
    __syncthreads();

    int side = 0;
    for (int kt = 0; kt < 256; ++kt) {
        const int k0 = kt * 32 + quad * 8;
        // A-inputs first (L1-hot) so their vmcnt wait doesn't drain staging
        f32x4 ee[8];
#pragma unroll
        for (int i = 0; i < 8; ++i) ee[i] = en[k0 + i];
        // staging loads for kt+1 (stay in flight through compute)
        const bool pf = (kt < 255);
        uint4 s0;
        if (pf) s0 = *(const uint4*)(sp + (kt + 1) * 32);

        // A-gen (register fragment, v5-verified mapping)
        unsigned au[4];
#pragma unroll
        for (int i = 0; i < 8; i += 2) {
            float sa = fmaf(pnc.x, ee[i].x, fmaf(pnc.y, ee[i].y, pnc.z * ee[i].z));
            float sb = fmaf(pnc.x, ee[i + 1].x, fmaf(pnc.y, ee[i + 1].y, pnc.z * ee[i + 1].z));
            float w0 = __builtin_amdgcn_exp2f(sa * 1.44269504f);
            float w1 = __builtin_amdgcn_exp2f(sb * 1.44269504f);
            unsigned u = pk_bf16(w0, w1);
            au[i >> 1] = u;
            float w0r = bits_to_f(u << 16), w1r = bits_to_f(u & 0xffff0000u);
            lp += w0r + w1r;
            if (donpe) {
                f32x4 p0 = ps[k0 + i], p1 = ps[k0 + i + 1];
                nxa = fmaf(w0r, p0.x, fmaf(w1r, p1.x, nxa));
                nya = fmaf(w0r, p0.y, fmaf(w1r, p1.y, nya));
                nza = fmaf(w0r, p0.z, fmaf(w1r, p1.z, nza));
            }
        }
        bf16x8 af = mk_bf16x8(au[0], au[1], au[2], au[3]);

        // MFMA over shared B (conflict-free lane*16 reads)
#pragma unroll
        for (int nf = 0; nf < NF; ++nf) {
            bf16x8 b = *(const bf16x8*)(&pbuf[side][nf * 512 + l * 8]);
            acc[nf] = __builtin_amdgcn_mfma_f32_16x16x32_bf16(af, b, acc[nf], 0, 0, 0);
        }

        if (pf) *(uint4*)(&pbuf[side ^ 1][t * 8]) = s0;
        __syncthreads();
        side ^= 1;
    }

    // row-sum across quads: lanes (col, quad*) share row wv*16+col
    float lsum = lp;
    lsum += __shfl_xor(lsum, 16);
    lsum += __shfl_xor(lsum, 32);
    if (donpe) {
        float sx = nxa; sx += __shfl_xor(sx, 16); sx += __shfl_xor(sx, 32);
        float sy = nya; sy += __shfl_xor(sy, 16); sy += __shfl_xor(sy, 32);
        float sz = nza; sz += __shfl_xor(sz, 16); sz += __shfl_xor(sz, 32);
        if (quad == 0) {
            float inv = 1.0f / lsum;
            float X = sx * inv, Y = sy * inv, Z = sz * inv;
            f32x4 o = {X, Y, Z, X * X + Y * Y + Z * Z};
            ((f32x4*)npe4)[mb + wv * 16 + col] = o;
        }
    }
    if (quad == 0) lbuf[wv * 16 + col] = lsum;
    __syncthreads();

    // memT[f][m] = acc / l  (D: row m = quad*4+reg, col f = lane&15)
    {
        f32x4 l4 = *(const f32x4*)(lbuf + wv * 16 + quad * 4);
        f32x4 inv4 = {1.0f / l4.x, 1.0f / l4.y, 1.0f / l4.z, 1.0f / l4.w};
        int mg = mb + wv * 16 + quad * 4;
#pragma unroll
        for (int nf = 0; nf < NF; ++nf) {
            int fg = fb * 128 + nf * 16 + col;
            uint2 o;
            o.x = pk_bf16(acc[nf].x * inv4.x, acc[nf].y * inv4.y);
            o.y = pk_bf16(acc[nf].z * inv4.z, acc[nf].w * inv4.w);
            *(uint2*)(memT + (size_t)fg * M_SZ + mg) = o;
        }
    }
}

// ---------------------------------------------------------------------------
// Kernel 4 (v6): register-A + LDS-shared B. BM=256 (8 waves x 2 mf),
// BN=256 (16 nf), BK=32, fb=bid&1 (XCD L2-affine 4MB memT half).
// memT traffic = unique = 1 GB (was 8 GB in v5, 2 GB in v1) -> ~154 us BW
// floor vs 133 us MFMA floor. Fragment-order LDS: conflict-free b128.
// ---------------------------------------------------------------------------
__launch_bounds__(512, 2)
__global__ void query_kernel(const float* __restrict__ qpos,
                             const float* __restrict__ npe4,
                             const unsigned short* __restrict__ memT,
                             float* __restrict__ out) {
    constexpr int NF = 16;                    // BN = 256
    __shared__ unsigned short pbuf[2][NF * 512];  // 16 KiB per side
    __shared__ float lbuf[256];

    const int t = threadIdx.x;
    const int wv = t >> 6, l = t & 63;
    const int col = l & 15, quad = l >> 4;
    const int bid = blockIdx.x;
    const int fb = bid & 1;
    const int qb = (bid >> 1) * 256;

    // per-lane q-row constants for the wave's 2 m-frags (rows wv*32+mf*16+col)
    float m2x[2], m2y[2], m2z[2], q2c[2];
#pragma unroll
    for (int mf = 0; mf < 2; ++mf) {
        int r = qb + wv * 32 + mf * 16 + col;
        float qx = qpos[(size_t)r * 3 + 0];
        float qy = qpos[(size_t)r * 3 + 1];
        float qz = qpos[(size_t)r * 3 + 2];
        q2c[mf] = qx * qx + qy * qy + qz * qz;
        m2x[mf] = -2.0f * qx; m2y[mf] = -2.0f * qy; m2z[mf] = -2.0f * qz;
    }

    const f32x4* nsrc = (const f32x4*)npe4;

    // staging: thread t owns chunks c0 = t and c1 = t+512 (1024 chunks of 16B)
    // chunk c: row = fb*256 + (c>>6)*16 + (c&15); k-chunk = (c>>4)&3
    const int c1 = t + 512;
    const unsigned short* sp0 =
        memT + (size_t)(fb * 256 + (t >> 6) * 16 + (t & 15)) * M_SZ + ((t >> 4) & 3) * 8;
    const unsigned short* sp1 =
        memT + (size_t)(fb * 256 + (c1 >> 6) * 16 + (c1 & 15)) * M_SZ + ((c1 >> 4) & 3) * 8;

    f32x4 acc[2][NF];
    const f32x4 zero4 = {0.f, 0.f, 0.f, 0.f};
#pragma unroll
    for (int mf = 0; mf < 2; ++mf)
#pragma unroll
        for (int nf = 0; nf < NF; ++nf) acc[mf][nf] = zero4;
    float lp2[2] = {0.f, 0.f};

    // prologue: stage kt = 0 into side 0
    {
        uint4 s0 = *(const uint4*)(sp0);
        uint4 s1 = *(const uint4*)(sp1);
        *(uint4*)(&pbuf[0][t * 8]) = s0;
        *(uint4*)(&pbuf[0][c1 * 8]) = s1;
    }
    __syncthreads();

    int side = 0;
    for (int kt = 0; kt < 256; ++kt) {
        const int k0 = kt * 32 + quad * 8;
        // A-inputs first (tiny, L1/L2-hot) so A-gen's wait leaves staging in flight
        f32x4 nn[8];
#pragma unroll
        for (int i = 0; i < 8; ++i) nn[i] = nsrc[k0 + i];
        const bool pf = (kt < 255);
        uint4 s0, s1;
        if (pf) {
            s0 = *(const uint4*)(sp0 + (kt + 1) * 32);
            s1 = *(const uint4*)(sp1 + (kt + 1) * 32);
        }

        // A-gen (register fragments, v5-verified mapping)
        bf16x8 af[2];
#pragma unroll
        for (int mf = 0; mf < 2; ++mf) {
            unsigned au[4];
#pragma unroll
            for (int i = 0; i < 8; i += 2) {
                float sa = fmaf(m2x[mf], nn[i].x, fmaf(m2y[mf], nn[i].y,
                           fmaf(m2z[mf], nn[i].z, q2c[mf] + nn[i].w)));
                float sb = fmaf(m2x[mf], nn[i + 1].x, fmaf(m2y[mf], nn[i + 1].y,
                           fmaf(m2z[mf], nn[i + 1].z, q2c[mf] + nn[i + 1].w)));
                sa = fmaxf(sa, 1e-12f); sb = fmaxf(sb, 1e-12f);
                float w0 = __builtin_amdgcn_exp2f(
                    __builtin_amdgcn_sqrtf(sa) * -1.44269504f);
                float w1 = __builtin_amdgcn_exp2f(
                    __builtin_amdgcn_sqrtf(sb) * -1.44269504f);
                unsigned u = pk_bf16(w0, w1);
                au[i >> 1] = u;
                lp2[mf] += bits_to_f(u << 16) + bits_to_f(u & 0xffff0000u);
            }
            af[mf] = mk_bf16x8(au[0], au[1], au[2], au[3]);
        }

        // MFMA over shared B (conflict-free lane*16 reads, reused for 2 mf)
#pragma unroll
        for (int nf = 0; nf < NF; ++nf) {
            bf16x8 b = *(const bf16x8*)(&pbuf[side][nf * 512 + l * 8]);
            acc[0][nf] = __builtin_amdgcn_mfma_f32_16x16x32_bf16(af[0], b, acc[0][nf], 0, 0, 0);
            acc[1][nf] = __builtin_amdgcn_mfma_f32_16x16x32_bf16(af[1], b, acc[1][nf], 0, 0, 0);
        }

        if (pf) {
            *(uint4*)(&pbuf[side ^ 1][t * 8]) = s0;
            *(uint4*)(&pbuf[side ^ 1][c1 * 8]) = s1;
        }
        __syncthreads();
        side ^= 1;
    }

    // row-sums across quads; redistribute via tiny LDS for the epilogue
#pragma unroll
    for (int mf = 0; mf < 2; ++mf) {
        float s = lp2[mf];
        s += __shfl_xor(s, 16);
        s += __shfl_xor(s, 32);
        if (quad == 0) lbuf[wv * 32 + mf * 16 + col] = s;
    }
    __syncthreads();

#pragma unroll
    for (int mf = 0; mf < 2; ++mf) {
        f32x4 l4 = *(const f32x4*)(lbuf + wv * 32 + mf * 16 + quad * 4);
        f32x4 inv4 = {1.0f / l4.x, 1.0f / l4.y, 1.0f / l4.z, 1.0f / l4.w};
        int qg = qb + wv * 32 + mf * 16 + quad * 4;
#pragma unroll
        for (int nf = 0; nf < NF; ++nf) {
            int fg = fb * 256 + nf * 16 + col;
            out[(size_t)(qg + 0) * F_DIM + fg] = acc[mf][nf].x * inv4.x;
            out[(size_t)(qg + 1) * F_DIM + fg] = acc[mf][nf].y * inv4.y;
            out[(size_t)(qg + 2) * F_DIM + fg] = acc[mf][nf].z * inv4.z;
            out[(size_t)(qg + 3) * F_DIM + fg] = acc[mf][nf].w * inv4.w;
        }
    }
}

// ---------------------------------------------------------------------------
// Workspace layout (bytes):
//   featT : [0,        8388608)   512x8192 bf16
//   memT  : [8388608, 16777216)   512x8192 bf16
//   npe4  : [16777216,16908288)   8192x4 fp32 (x,y,z,|npe|^2)
//   pn4   : [16908288,17039360)
//   en4   : [17039360,17170432)
//   pos4  : [17170432,17301504)
// ---------------------------------------------------------------------------
extern "C" void kernel_launch(void* const* d_in, const int* in_sizes, int n_in,
                              void* d_out, int out_size, void* d_ws, size_t ws_size,
                              hipStream_t stream) {
    const float* features  = (const float*)d_in[0];
    const float* positions = (const float*)d_in[1];
    const float* qpos      = (const float*)d_in[2];
    const float* pemb      = (const float*)d_in[3];
    float* out = (float*)d_out;
    char* ws = (char*)d_ws;

    unsigned short* featT = (unsigned short*)(ws);
    unsigned short* memT  = (unsigned short*)(ws + 8388608);
    float* npe4 = (float*)(ws + 16777216);
    float* pn4  = (float*)(ws + 16908288);
    float* en4  = (float*)(ws + 17039360);
    float* pos4 = (float*)(ws + 17170432);

    hipLaunchKernelGGL(prep_kernel, dim3(M_SZ / 256), dim3(256), 0, stream,
                       positions, pemb, pn4, en4, pos4);
    hipLaunchKernelGGL(transpose_kernel, dim3(M_SZ / 64, F_DIM / 64), dim3(256), 0, stream,
                       features, featT);
    hipLaunchKernelGGL(build_memory_kernel, dim3((M_SZ / 128) * 4), dim3(512), 0, stream,
                       pn4, en4, pos4, featT, memT, npe4);
    hipLaunchKernelGGL(query_kernel, dim3((N_Q / 256) * 2), dim3(512), 0, stream,
                       qpos, npe4, memT, out);
}